// Round 4
// baseline (607.760 us; speedup 1.0000x reference)
//
#include <hip/hip_runtime.h>

#define LN_EPS 1e-5f

constexpr int DIM    = 768;
constexpr int NSPLIT = 4;              // waves per block, each covers SEG cols
constexpr int BLOCK  = NSPLIT * 64;    // 256 threads
constexpr int SEG    = DIM / NSPLIT;   // 192
constexpr int C      = 16;             // cols per chunk per feature
constexpr int NCH    = SEG / C;        // 12 chunks
constexpr int WBUF   = 2 * C * 64;     // floats per wave tile (f0+f1) = 2048
// total LDS = NSPLIT*WBUF = 8192 floats = 32 KB -> 4 blocks/CU, 16 waves/CU

// s_waitcnt immediates (gfx9 layout: vmcnt[3:0]+[15:14], expcnt[6:4], lgkmcnt[11:8])
#define WAIT_VM0   0x0F70   // vmcnt(0), ignore exp/lgkm
#define WAIT_LGKM0 0xC07F   // lgkmcnt(0), ignore vm/exp

typedef const __attribute__((address_space(1))) void* gas_ptr;
typedef __attribute__((address_space(3))) void*       las_ptr;

__launch_bounds__(BLOCK, 4)   // cap 128 VGPR; LDS allows 4 blocks/CU
__global__ void fused_concat_linear(const float* __restrict__ feat,
                                    const float* __restrict__ W_int,
                                    const float* __restrict__ W_stim,
                                    const float* __restrict__ trans,
                                    const float* __restrict__ ln_w,
                                    const float* __restrict__ ln_b,
                                    const float* __restrict__ W_out,
                                    const float* __restrict__ b_out,
                                    float* __restrict__ out,
                                    int B)
{
    __shared__ float lds[NSPLIT * WBUF];   // wave-private tiles; reused as sP after barrier

    const int lane = threadIdx.x & 63;
    const int wave = __builtin_amdgcn_readfirstlane(threadIdx.x >> 6);

    const int row = blockIdx.x * 64 + lane;
    const int rr  = min(row, B - 1);
    const float* frow = feat + (size_t)rr * (2 * DIM);

    float* wbuf = lds + wave * WBUF;   // [feature][m][lane][4]: f*1024 + m*256 + 4*lane

    float accL[9], accT[9];
#pragma unroll
    for (int a = 0; a < 9; ++a) { accL[a] = 0.f; accT[a] = 0.f; }

    for (int ch = 0; ch < NCH; ++ch) {
        const int c0 = wave * SEG + ch * C;   // wave-uniform column base

        // ---- async DMA: lane i's 16B lands at lds_base + 16*i (HW rule) ----
#pragma unroll
        for (int m = 0; m < 4; ++m) {
            __builtin_amdgcn_global_load_lds((gas_ptr)(frow + c0 + 4 * m),
                                             (las_ptr)(wbuf + m * 256), 16, 0, 0);
            __builtin_amdgcn_global_load_lds((gas_ptr)(frow + DIM + c0 + 4 * m),
                                             (las_ptr)(wbuf + 1024 + m * 256), 16, 0, 0);
        }
        __builtin_amdgcn_s_waitcnt(WAIT_VM0);   // DMA complete (weights use SMEM/lgkm, not vmcnt)

        // ---- consume tile: lane reads its own row's 16+16 floats (contiguous -> no conflicts) ----
#pragma unroll
        for (int m = 0; m < 4; ++m) {
            const float4 x0 = *(const float4*)(wbuf + m * 256 + 4 * lane);
            const float4 x1 = *(const float4*)(wbuf + 1024 + m * 256 + 4 * lane);
#pragma unroll
            for (int a = 0; a < 9; ++a) {
                const float4 w0 = *(const float4*)(W_int + a * DIM + c0 + 4 * m);  // uniform -> s_load
                float sL = accL[a];
                sL = fmaf(x0.x, w0.x, sL);
                sL = fmaf(x0.y, w0.y, sL);
                sL = fmaf(x0.z, w0.z, sL);
                sL = fmaf(x0.w, w0.w, sL);
                accL[a] = sL;
                const float4 w1 = *(const float4*)(W_stim + a * DIM + c0 + 4 * m); // uniform -> s_load
                float sT = accT[a];
                sT = fmaf(x1.x, w1.x, sT);
                sT = fmaf(x1.y, w1.y, sT);
                sT = fmaf(x1.z, w1.z, sT);
                sT = fmaf(x1.w, w1.w, sT);
                accT[a] = sT;
            }
        }
        __builtin_amdgcn_s_waitcnt(WAIT_LGKM0); // drain ds_reads before DMA reuses the buffer
    }

    // ---- combine the 4 column-quarters via LDS (reuse tile memory) ----
    __syncthreads();                      // all waves done with their tiles
    float* sP = lds;                      // [wave][18][64] = 4608 floats
#pragma unroll
    for (int a = 0; a < 9; ++a) {
        sP[(wave * 18 + a) * 64 + lane]     = accL[a];
        sP[(wave * 18 + 9 + a) * 64 + lane] = accT[a];
    }
    __syncthreads();

    if (wave == 0) {
        float lastv[9], thisv[9];
#pragma unroll
        for (int a = 0; a < 9; ++a) {
            lastv[a] = (sP[(0 * 18 + a) * 64 + lane] + sP[(1 * 18 + a) * 64 + lane])
                     + (sP[(2 * 18 + a) * 64 + lane] + sP[(3 * 18 + a) * 64 + lane]);
            thisv[a] = (sP[(0 * 18 + 9 + a) * 64 + lane] + sP[(1 * 18 + 9 + a) * 64 + lane])
                     + (sP[(2 * 18 + 9 + a) * 64 + lane] + sP[(3 * 18 + 9 + a) * 64 + lane]);
        }

        // bil[k] = sum_{a,j} this[a]*last[j]*trans[a][j][k]   (trans: uniform s_loads)
        float bil[9];
#pragma unroll
        for (int k = 0; k < 9; ++k) bil[k] = 0.f;
#pragma unroll
        for (int a = 0; a < 9; ++a) {
#pragma unroll
            for (int j = 0; j < 9; ++j) {
                const float p = thisv[a] * lastv[j];
                const float* tp = trans + (a * 81 + j * 9);
#pragma unroll
                for (int k = 0; k < 9; ++k) bil[k] = fmaf(p, tp[k], bil[k]);
            }
        }

        // LayerNorm(9)
        float mu = 0.f;
#pragma unroll
        for (int k = 0; k < 9; ++k) mu += bil[k];
        mu *= (1.f / 9.f);
        float var = 0.f;
#pragma unroll
        for (int k = 0; k < 9; ++k) { const float d = bil[k] - mu; var = fmaf(d, d, var); }
        var *= (1.f / 9.f);
        const float rs = rsqrtf(var + LN_EPS);

        float lnv[9];
#pragma unroll
        for (int j = 0; j < 9; ++j)
            lnv[j] = fmaf((bil[j] - mu) * rs, ln_w[j], ln_b[j]);

        if (row < B) {
#pragma unroll
            for (int i = 0; i < 9; ++i) {
                float o = b_out[i];
#pragma unroll
                for (int a = 0; a < 9; ++a) o = fmaf(thisv[a], W_out[i * 18 + a], o);
#pragma unroll
                for (int j = 0; j < 9; ++j) o = fmaf(lnv[j], W_out[i * 18 + 9 + j], o);
                out[(size_t)row * 9 + i] = o;
            }
        }
    }
}

extern "C" void kernel_launch(void* const* d_in, const int* in_sizes, int n_in,
                              void* d_out, int out_size, void* d_ws, size_t ws_size,
                              hipStream_t stream) {
    const float* feat   = (const float*)d_in[0];
    const float* W_int  = (const float*)d_in[1];
    const float* W_stim = (const float*)d_in[2];
    const float* trans  = (const float*)d_in[3];
    const float* ln_w   = (const float*)d_in[4];
    const float* ln_b   = (const float*)d_in[5];
    const float* W_out  = (const float*)d_in[6];
    const float* b_out  = (const float*)d_in[7];
    float* out = (float*)d_out;

    const int B = in_sizes[0] / (2 * DIM);    // 65536
    const int grid = (B + 63) / 64;           // 1024 blocks: exactly 4 resident per CU

    fused_concat_linear<<<grid, BLOCK, 0, stream>>>(
        feat, W_int, W_stim, trans, ln_w, ln_b, W_out, b_out, out, B);
}